// Round 1
// baseline (113.150 us; speedup 1.0000x reference)
//
#include <hip/hip_runtime.h>
#include <math.h>

#define G 32
#define IMG_W 512
#define IMG_H 512
#define NPIX (IMG_W * IMG_H)

__device__ __forceinline__ int quantize(float v) {
    int q = (int)(v * 31.0f);   // matches (img*31).astype(int32): rn multiply, trunc convert
    return q > 31 ? 31 : q;
}

// One block per image (128 images: 0..63 = x, 64..127 = y).
// Builds 4 GLCM histograms (32x32) in LDS via atomics, then reduces the
// 3 texture features per angle in-block and writes 12 floats to feats[img*12].
__global__ __launch_bounds__(1024) void glcm_feat_kernel(
    const float* __restrict__ x, const float* __restrict__ y,
    float* __restrict__ feats)
{
    __shared__ unsigned int hist[4 * G * G];   // 16 KB
    __shared__ float red[4][16][3];

    const int img = blockIdx.x;
    const float* base = (img < 64) ? (x + (size_t)img * NPIX)
                                   : (y + (size_t)(img - 64) * NPIX);
    const int t = threadIdx.x;

    #pragma unroll
    for (int k = 0; k < 4; ++k) hist[t + k * 1024] = 0u;
    __syncthreads();

    unsigned int* h0 = hist;
    unsigned int* h1 = hist + 1024;
    unsigned int* h2 = hist + 2048;
    unsigned int* h3 = hist + 3072;

    // thread -> (row, column half). All 512 rows, 2 halves of 256 cols.
    const int row = t >> 1;
    const int c0 = (t & 1) << 8;
    const bool rowv = (row < IMG_H - 1);
    const float* rp = base + (size_t)row * IMG_W;
    const float* rq = rp + IMG_W;

    // sliding-lag pair emission: each chunk of 4 pixels emits pairs whose
    // "second" element lies in the chunk (A0/A1) or whose anchor is in the
    // chunk (A2/A3). Lags pa=q[r][cc-1], pb=q[r+1][cc-1].
    int pa = 0, pb = 0;
    bool lagv = (c0 != 0);
    if (lagv) {
        pa = quantize(rp[c0 - 1]);
        if (rowv) pb = quantize(rq[c0 - 1]);
    }
    for (int cc = c0; cc < c0 + 256; cc += 4) {
        const float4 fa = *reinterpret_cast<const float4*>(rp + cc);
        const int a0 = quantize(fa.x), a1 = quantize(fa.y),
                  a2 = quantize(fa.z), a3 = quantize(fa.w);
        // angle 0: (0,1)
        if (lagv) atomicAdd(&h0[pa * G + a0], 1u);
        atomicAdd(&h0[a0 * G + a1], 1u);
        atomicAdd(&h0[a1 * G + a2], 1u);
        atomicAdd(&h0[a2 * G + a3], 1u);
        if (rowv) {
            const float4 fb = *reinterpret_cast<const float4*>(rq + cc);
            const int b0 = quantize(fb.x), b1 = quantize(fb.y),
                      b2 = quantize(fb.z), b3 = quantize(fb.w);
            if (lagv) {
                atomicAdd(&h1[pa * G + b0], 1u);   // (r,cc-1)->(r+1,cc)
                atomicAdd(&h3[a0 * G + pb], 1u);   // (r,cc)->(r+1,cc-1)
            }
            // angle 1: (1,1)
            atomicAdd(&h1[a0 * G + b1], 1u);
            atomicAdd(&h1[a1 * G + b2], 1u);
            atomicAdd(&h1[a2 * G + b3], 1u);
            // angle 2: (1,0)
            atomicAdd(&h2[a0 * G + b0], 1u);
            atomicAdd(&h2[a1 * G + b1], 1u);
            atomicAdd(&h2[a2 * G + b2], 1u);
            atomicAdd(&h2[a3 * G + b3], 1u);
            // angle 3: (1,-1)
            atomicAdd(&h3[a1 * G + b0], 1u);
            atomicAdd(&h3[a2 * G + b1], 1u);
            atomicAdd(&h3[a3 * G + b2], 1u);
            pb = b3;
        }
        pa = a3;
        lagv = true;
    }
    __syncthreads();

    // Feature reduction. Thread t owns bin (i,j) of each angle's histogram.
    const int i = t >> 5, j = t & 31;
    const int d2 = (i - j) * (i - j);
    const float inv = 1.0f / (1.0f + (float)d2);
    const int lane = t & 63, wave = t >> 6;
    #pragma unroll
    for (int a = 0; a < 4; ++a) {
        const float h  = (float)hist[a * 1024 + i * G + j];
        const float ht = (float)hist[a * 1024 + j * G + i];
        float cs = h * (float)d2;
        float hs = h * inv;
        float es = (h + ht) * (h + ht);
        #pragma unroll
        for (int off = 32; off; off >>= 1) {
            cs += __shfl_down(cs, off);
            hs += __shfl_down(hs, off);
            es += __shfl_down(es, off);
        }
        if (lane == 0) { red[a][wave][0] = cs; red[a][wave][1] = hs; red[a][wave][2] = es; }
    }
    __syncthreads();
    if (t < 4) {
        float cs = 0.f, hs = 0.f, es = 0.f;
        for (int w = 0; w < 16; ++w) {
            cs += red[t][w][0]; hs += red[t][w][1]; es += red[t][w][2];
        }
        // pair counts per angle: (0,1):512*511, (1,1):511*511, (1,0):511*512, (1,-1):511*511
        const float Na = (t == 0 || t == 2) ? 261632.0f : 261121.0f;
        float* o = feats + img * 12 + t * 3;
        o[0] = cs / Na;                    // contrast
        o[1] = sqrtf(es) / (2.0f * Na);    // energy
        o[2] = hs / Na;                    // homogeneity
    }
}

__global__ void loss_kernel(const float* __restrict__ feats, float* __restrict__ out)
{
    const int t = threadIdx.x;  // 256 threads
    float s = 0.0f;
    for (int k = t; k < 768; k += 256)
        s += fabsf(feats[k] - feats[768 + k]);
    #pragma unroll
    for (int off = 32; off; off >>= 1) s += __shfl_down(s, off);
    __shared__ float red[4];
    if ((t & 63) == 0) red[t >> 6] = s;
    __syncthreads();
    if (t == 0) out[0] = (red[0] + red[1] + red[2] + red[3]) * (1.0f / 768.0f);
}

extern "C" void kernel_launch(void* const* d_in, const int* in_sizes, int n_in,
                              void* d_out, int out_size, void* d_ws, size_t ws_size,
                              hipStream_t stream) {
    const float* x = (const float*)d_in[0];
    const float* y = (const float*)d_in[1];
    float* feats = (float*)d_ws;           // 128 images * 12 floats = 6 KB
    float* out = (float*)d_out;

    hipLaunchKernelGGL(glcm_feat_kernel, dim3(128), dim3(1024), 0, stream,
                       x, y, feats);
    hipLaunchKernelGGL(loss_kernel, dim3(1), dim3(256), 0, stream, feats, out);
}